// Round 5
// baseline (635.174 us; speedup 1.0000x reference)
//
#include <hip/hip_runtime.h>
#include <cstddef>

#define NBLK 512

typedef __attribute__((ext_vector_type(8))) short bf16x8;
typedef __attribute__((ext_vector_type(4))) float f32x4;

__device__ __forceinline__ float lrelu(float x) { return x >= 0.f ? x : 0.2f * x; }
// RNE float -> bf16
__device__ __forceinline__ unsigned short f2bf(float x) {
    unsigned u = __float_as_uint(x);
    u += 0x7FFFu + ((u >> 16) & 1u);
    return (unsigned short)(u >> 16);
}
__device__ __forceinline__ float bf2f(unsigned short u) {
    return __uint_as_float((unsigned)u << 16);
}

// ---------------------------------------------------------------------------------------
// Grid barrier: monotonic device-scope counter. Counter starts at 0 (memset node before
// the kernel each iteration). Release: __threadfence() flushes this XCD's L2 before the
// arrive-add; polls are relaxed agent-scope atomic loads (coherent-point reads, no cache
// staleness); acquire: __threadfence() after the wait invalidates stale lines.
// Co-residency of all 512 blocks is guaranteed by __launch_bounds__(512,4):
// 16 waves/CU = 2 blocks/CU x 256 CU = 512; LDS 47KB < 80KB budget for 2 blocks.
// ---------------------------------------------------------------------------------------
__device__ __forceinline__ void gbar(unsigned* bar, unsigned target) {
    __syncthreads();
    if (threadIdx.x == 0) {
        __threadfence();
        __hip_atomic_fetch_add(bar, 1u, __ATOMIC_RELAXED, __HIP_MEMORY_SCOPE_AGENT);
        while (__hip_atomic_load(bar, __ATOMIC_RELAXED, __HIP_MEMORY_SCOPE_AGENT) < target)
            __builtin_amdgcn_s_sleep(8);
        __threadfence();
    }
    __syncthreads();
}

// ---------------------------------------------------------------------------------------
// W (K x 640 fp32) -> WT (640 x K bf16), one 64-col n-tile, 512 threads.
// ---------------------------------------------------------------------------------------
__device__ __forceinline__ void wtrans(const float* __restrict__ W,
                                       unsigned short* __restrict__ WT,
                                       int K, int nt, int t) {
    int n = nt * 64 + (t & 63);
    for (int kg = t >> 6; kg < K / 8; kg += 8) {
        bf16x8 v;
#pragma unroll
        for (int e = 0; e < 8; ++e) v[e] = (short)f2bf(W[(size_t)(kg * 8 + e) * 640 + n]);
        *(bf16x8*)&WT[(size_t)n * K + kg * 8] = v;
    }
}

// pack y_bonds -> maskp: one uint (4 items x 5 r-bits) per call.
__device__ __forceinline__ void maskpack(const int* __restrict__ bonds,
                                         unsigned char* __restrict__ maskp, int gt) {
    const int4* p = (const int4*)(bonds + (size_t)gt * 20);
    int4 q0 = p[0], q1 = p[1], q2 = p[2], q3 = p[3], q4 = p[4];
    int v[20] = {q0.x, q0.y, q0.z, q0.w, q1.x, q1.y, q1.z, q1.w,
                 q2.x, q2.y, q2.z, q2.w, q3.x, q3.y, q3.z, q3.w,
                 q4.x, q4.y, q4.z, q4.w};
    unsigned m = 0;
#pragma unroll
    for (int k = 0; k < 4; ++k)
#pragma unroll
        for (int r = 0; r < 5; ++r)
            m |= (v[k * 5 + r] == 1) ? (1u << (k * 8 + r)) : 0u;
    *(unsigned*)&maskp[(size_t)gt * 4] = m;
}

// ---------------------------------------------------------------------------------------
// gemm body: virtual 256-thread block (t in [0,256)), barrier-free, so two run per real
// block (halves). Identical math/layout to the verified round-4 k_gemm_h, incl. the
// XCD-affinity swizzle l -> (mt, nt).
// ---------------------------------------------------------------------------------------
template <int K, int MODE>
__device__ __forceinline__ void gemm_body(int l, int t,
                                          const float* __restrict__ Af32,
                                          const unsigned short* __restrict__ Ab,
                                          const unsigned short* __restrict__ WTg,
                                          const float* __restrict__ bias,
                                          const float* __restrict__ avec,
                                          float* __restrict__ srcp,
                                          float* __restrict__ dstp,
                                          unsigned short* __restrict__ hTf) {
    const int mt = (l & 7) * 16 + ((l >> 3) & 15);   // [0,128)
    const int nt = l >> 7;                            // [0,10)
    const int n0 = nt * 64, m0 = mt * 64;
    const int w = t >> 6, lane = t & 63;
    const int colg = lane & 15, rquad = lane >> 4;
    const int m = m0 + w * 16 + colg;
    const int koff = rquad * 8;

    f32x4 acc[4] = {};
#pragma unroll
    for (int kk = 0; kk < K; kk += 32) {
        bf16x8 af;
        size_t off = (size_t)m * K + kk + koff;
        if (MODE == 1) {
            af = *(const bf16x8*)&Ab[off];
        } else {
            float4 q0 = *(const float4*)&Af32[off];
            float4 q1 = *(const float4*)&Af32[off + 4];
            af[0] = (short)f2bf(q0.x); af[1] = (short)f2bf(q0.y);
            af[2] = (short)f2bf(q0.z); af[3] = (short)f2bf(q0.w);
            af[4] = (short)f2bf(q1.x); af[5] = (short)f2bf(q1.y);
            af[6] = (short)f2bf(q1.z); af[7] = (short)f2bf(q1.w);
        }
#pragma unroll
        for (int ct = 0; ct < 4; ++ct) {
            bf16x8 bfv = *(const bf16x8*)&WTg[(size_t)(n0 + ct * 16 + colg) * K + kk + koff];
            acc[ct] = __builtin_amdgcn_mfma_f32_16x16x32_bf16(af, bfv, acc[ct], 0, 0, 0);
        }
    }

    const int r = n0 >> 7, chalf = n0 & 127;
    const int b = m0 >> 8, jb = m0 & 255;
    float val[4][4];
    float ssum[4] = {0.f, 0.f, 0.f, 0.f}, dsum[4] = {0.f, 0.f, 0.f, 0.f};
#pragma unroll
    for (int ct = 0; ct < 4; ++ct) {
        int cg = chalf + ct * 16 + colg;
        float bv = bias[n0 + ct * 16 + colg];
        float asr = avec[r * 256 + cg];
        float ads = avec[r * 256 + 128 + cg];
#pragma unroll
        for (int reg = 0; reg < 4; ++reg) {
            float v = acc[ct][reg] + bv;
            val[ct][reg] = v;
            ssum[reg] += v * asr;
            dsum[reg] += v * ads;
        }
    }
#pragma unroll
    for (int mk = 1; mk < 16; mk <<= 1)
#pragma unroll
        for (int reg = 0; reg < 4; ++reg) {
            ssum[reg] += __shfl_xor(ssum[reg], mk);
            dsum[reg] += __shfl_xor(dsum[reg], mk);
        }
    if (colg == 0) {
        int nhalf = (n0 >> 6) & 1;
#pragma unroll
        for (int reg = 0; reg < 4; ++reg) {
            int row = m0 + w * 16 + rquad * 4 + reg;
            srcp[nhalf * 40960 + row * 5 + r] = ssum[reg];
            dstp[nhalf * 40960 + row * 5 + r] = dsum[reg];
        }
    }
    {
        const int joct = (jb >> 3) + w * 2 + (rquad >> 1);
        const size_t tile = (size_t)((b * 5 + r) * 32 + joct) * 1024;
        const int sub = (rquad & 1) * 4;
#pragma unroll
        for (int ct = 0; ct < 4; ++ct) {
            int c = chalf + ct * 16 + colg;
            uint2 pk;
            pk.x = (unsigned)f2bf(val[ct][0]) | ((unsigned)f2bf(val[ct][1]) << 16);
            pk.y = (unsigned)f2bf(val[ct][2]) | ((unsigned)f2bf(val[ct][3]) << 16);
            *(uint2*)&hTf[tile + (size_t)c * 8 + sub] = pk;
        }
    }
}

// ---------------------------------------------------------------------------------------
// agg body: 512 threads, 1:1 with a real block (l = rb), identical to verified round-4
// k_agg incl. XCD-affinity swizzle. LDS passed in (shared union across phases).
// ---------------------------------------------------------------------------------------
template <int FINAL>
__device__ __forceinline__ void agg_body(int l, int t, unsigned char* SM,
                                         const unsigned short* __restrict__ hTf,
                                         const float* __restrict__ srcp,
                                         const float* __restrict__ dstp,
                                         const unsigned char* __restrict__ maskp,
                                         unsigned short* __restrict__ Ab,
                                         float* __restrict__ poolS,
                                         float* __restrict__ poolM) {
    unsigned short* Ps = (unsigned short*)SM;         // 40960 B
    float* Ds2l = (float*)(SM + 40960);               // 5120 B
    float* Ss   = (float*)(SM + 46080);               // 320 B
    float* Zw   = (float*)(SM + 46400);               // 512 B
    float* Zrow = (float*)(SM + 46912);               // 64 B

    const int b = (l & 7) * 4 + ((l >> 3) & 3);       // [0,32), XCD(b)=b/4
    const int itile = l >> 5;                          // [0,16)
    const int ib = b * 256 + itile * 16;
    const int w = t >> 6, lane = t & 63;
    const int colg = lane & 15, rquad = lane >> 4;
    const int c = w * 16 + colg;
    const size_t bbase = (size_t)(b * 5) * 32 * 1024;

    if (t < 80) Ss[t] = srcp[(size_t)ib * 5 + t] + srcp[40960 + (size_t)ib * 5 + t];
    for (int idx = t; idx < 1280; idx += 512) {
        int jl = idx & 255, rr = idx >> 8;
        size_t o = (size_t)(b * 256 + jl) * 5 + rr;
        Ds2l[rr * 256 + jl] = dstp[o] + dstp[40960 + o];
    }
    bf16x8 pre[4];
#pragma unroll
    for (int s = 0; s < 4; ++s)
        pre[s] = *(const bf16x8*)&hTf[bbase + (size_t)(s * 4 + rquad) * 1024 + (size_t)c * 8];
    __syncthreads();

    {
        const int i = t & 15;
        const int kq = (t >> 4) & 3;
        float esum = 0.f;
#pragma unroll
        for (int it = 0; it < 5; ++it) {
            int p = it * 512 + t;
            int s = p >> 6;
            int k0 = s * 32 + kq * 8;
            int rr = k0 >> 8, j0 = k0 & 255;
            uint2 mk8 = *(const uint2*)&maskp[((size_t)(ib + i) << 8) + j0];
            float sv = Ss[i * 5 + rr];
            float4 d0 = *(const float4*)&Ds2l[rr * 256 + j0];
            float4 d1 = *(const float4*)&Ds2l[rr * 256 + j0 + 4];
            float dv[8] = {d0.x, d0.y, d0.z, d0.w, d1.x, d1.y, d1.z, d1.w};
            bf16x8 pv;
#pragma unroll
            for (int e = 0; e < 8; ++e) {
                unsigned mb = ((e < 4 ? (mk8.x >> (8 * e)) : (mk8.y >> (8 * (e - 4)))) >> rr) & 1u;
                float vv = lrelu(sv + dv[e]);
                float ev = mb ? __expf(vv) : 0.f;
                unsigned short q = f2bf(ev);
                pv[e] = (short)q;
                esum += __uint_as_float((unsigned)q << 16);
            }
            *(bf16x8*)&Ps[p * 8] = pv;
        }
        esum += __shfl_xor(esum, 16);
        esum += __shfl_xor(esum, 32);
        if (lane < 16) Zw[w * 16 + (lane & 15)] = esum;
    }
    __syncthreads();
    if (t < 16) {
        float z = 0.f;
#pragma unroll
        for (int ww = 0; ww < 8; ++ww) z += Zw[ww * 16 + t];
        Zrow[t] = 1.f / z;
    }

    f32x4 acc0 = {}, acc1 = {};
#pragma unroll
    for (int s = 0; s < 8; ++s) {
        bf16x8 af = *(const bf16x8*)&Ps[(s * 64 + lane) * 8];
        bf16x8 bfv;
        if (s < 4) bfv = pre[s];
        else bfv = *(const bf16x8*)&hTf[bbase + (size_t)((s & 7) * 4 + rquad) * 1024 + (size_t)c * 8];
        if (s & 1) acc1 = __builtin_amdgcn_mfma_f32_16x16x32_bf16(af, bfv, acc1, 0, 0, 0);
        else       acc0 = __builtin_amdgcn_mfma_f32_16x16x32_bf16(af, bfv, acc0, 0, 0, 0);
    }
#pragma unroll 8
    for (int s = 8; s < 40; ++s) {
        bf16x8 af = *(const bf16x8*)&Ps[(s * 64 + lane) * 8];
        bf16x8 bfv = *(const bf16x8*)&hTf[bbase +
            (size_t)((s >> 3) * 32 + (s & 7) * 4 + rquad) * 1024 + (size_t)c * 8];
        if (s & 1) acc1 = __builtin_amdgcn_mfma_f32_16x16x32_bf16(af, bfv, acc1, 0, 0, 0);
        else       acc0 = __builtin_amdgcn_mfma_f32_16x16x32_bf16(af, bfv, acc0, 0, 0, 0);
    }
    __syncthreads();
    const int irow = ib + rquad * 4;
    if (FINAL) {
        float ps = 0.f, pm = -3.4e38f;
#pragma unroll
        for (int reg = 0; reg < 4; ++reg) {
            float v = (acc0[reg] + acc1[reg]) * Zrow[rquad * 4 + reg];
            ps += v;
            pm = fmaxf(pm, v);
        }
        ps += __shfl_xor(ps, 16);
        ps += __shfl_xor(ps, 32);
        pm = fmaxf(pm, __shfl_xor(pm, 16));
        pm = fmaxf(pm, __shfl_xor(pm, 32));
        if (rquad == 0) {
            poolS[(size_t)(b * 16 + itile) * 128 + c] = ps;
            poolM[(size_t)(b * 16 + itile) * 128 + c] = pm;
        }
    } else {
#pragma unroll
        for (int reg = 0; reg < 4; ++reg) {
            float v = (acc0[reg] + acc1[reg]) * Zrow[rquad * 4 + reg];
            Ab[(size_t)(irow + reg) * 128 + c] = f2bf(lrelu(v));
        }
    }
}

// mlp1 body: virtual 256-thread block vb in [0,160): kg = vb%5, b = vb/5. zs is per-half.
__device__ __forceinline__ void mlp1_body(int vb, int t, float* zs,
                                          const float* __restrict__ x,
                                          const float* __restrict__ poolS,
                                          const float* __restrict__ poolM,
                                          const float* __restrict__ We1,
                                          float* __restrict__ z1p) {
    const int kg = vb % 5, b = vb / 5;
    if (kg < 4) {
        zs[t] = x[(size_t)b * 1024 + kg * 256 + t];
    } else if (t < 128) {
        float s = 0.f;
#pragma unroll
        for (int it = 0; it < 16; ++it) s += poolS[(size_t)(b * 16 + it) * 128 + t];
        zs[t] = s * (1.f / 256.f);
    } else {
        int f = t - 128;
        float mx = -3.4e38f;
#pragma unroll
        for (int it = 0; it < 16; ++it) mx = fmaxf(mx, poolM[(size_t)(b * 16 + it) * 128 + f]);
        zs[t] = mx;
    }
    __syncthreads();
    float s = 0.f;
#pragma unroll 8
    for (int k = 0; k < 256; ++k) s += zs[k] * We1[(size_t)(kg * 256 + k) * 256 + t];
    z1p[(size_t)(b * 5 + kg) * 256 + t] = s;
}

// mlp2 body: 512 threads, b = rb; barriers uniform within block.
__device__ __forceinline__ void mlp2_body(int b, int t, unsigned char* SM,
                                          const float* __restrict__ z1p,
                                          const float* __restrict__ be1,
                                          const float* __restrict__ We2,
                                          const float* __restrict__ be2,
                                          const float* __restrict__ We3,
                                          const float* __restrict__ be3,
                                          float* __restrict__ out) {
    float* z1s = (float*)SM;              // 1024 B
    float* s2p = (float*)(SM + 1024);     // 1024 B
    float* z2s = (float*)(SM + 2048);     // 128 B
    if (t < 256) {
        float s = be1[t];
#pragma unroll
        for (int kg = 0; kg < 5; ++kg) s += z1p[(size_t)(b * 5 + kg) * 256 + t];
        z1s[t] = lrelu(s);
    }
    __syncthreads();
    if (t < 256) {
        int o = t & 31, g = t >> 5;
        float p = 0.f;
#pragma unroll
        for (int k = 0; k < 32; ++k) p += z1s[g * 32 + k] * We2[(g * 32 + k) * 32 + o];
        s2p[g * 32 + o] = p;
    }
    __syncthreads();
    if (t < 32) {
        float s2 = be2[t];
#pragma unroll
        for (int g = 0; g < 8; ++g) s2 += s2p[g * 32 + t];
        z2s[t] = lrelu(s2);
    }
    __syncthreads();
    if (t == 0) {
        float s3 = be3[0];
#pragma unroll
        for (int k = 0; k < 32; ++k) s3 += z2s[k] * We3[k];
        out[b] = s3;
    }
}

// =======================================================================================
// Persistent mega-kernel: 512 blocks x 512 threads, 9 phases, 8 grid barriers.
// P0: WT1            P1: gemm1 || maskpack || WT2/WT3     P2: agg1
// P3: gemm2          P4: agg2          P5: gemm3          P6: agg3(pool)
// P7: mlp1 (160 virtual)               P8: mlp2 (32 blocks)
// =======================================================================================
__global__ __launch_bounds__(512, 4) void k_mega(
    const float* __restrict__ x, const float* __restrict__ y_atoms,
    const int* __restrict__ bonds,
    const float* __restrict__ W1, const float* __restrict__ b1, const float* __restrict__ a1,
    const float* __restrict__ W2, const float* __restrict__ b2, const float* __restrict__ a2,
    const float* __restrict__ W3, const float* __restrict__ b3, const float* __restrict__ a3,
    const float* __restrict__ We1, const float* __restrict__ be1,
    const float* __restrict__ We2, const float* __restrict__ be2,
    const float* __restrict__ We3, const float* __restrict__ be3,
    unsigned char* __restrict__ maskp, float* __restrict__ srcp, float* __restrict__ dstp,
    unsigned short* __restrict__ Ab, unsigned short* __restrict__ hTf,
    unsigned short* __restrict__ WT1, unsigned short* __restrict__ WT2,
    unsigned short* __restrict__ WT3,
    float* __restrict__ poolS, float* __restrict__ poolM, float* __restrict__ z1p,
    unsigned* bar, float* __restrict__ out) {
    __shared__ __align__(16) unsigned char SM[46976];
    const int rb = blockIdx.x;
    const int t = threadIdx.x;
    const int hb = t >> 8, t2 = t & 255;

    // ---- P0: WT1 ----
    if (rb < 10) wtrans(W1, WT1, 64, rb, t);
    gbar(bar, NBLK * 1);

    // ---- P1: gemm1 + mask pack + WT2/WT3 ----
    for (int vb = rb * 2 + hb; vb < 1280; vb += 1024)
        gemm_body<64, 0>(vb, t2, y_atoms, nullptr, WT1, b1, a1, srcp, dstp, hTf);
    if (rb >= 480 && rb < 490)      wtrans(W2, WT2, 128, rb - 480, t);
    else if (rb >= 490 && rb < 500) wtrans(W3, WT3, 128, rb - 490, t);
    {
        int gt = rb * 512 + t;
        maskpack(bonds, maskp, gt);
        maskpack(bonds, maskp, gt + 262144);
    }
    gbar(bar, NBLK * 2);

    // ---- P2: agg1 ----
    agg_body<0>(rb, t, SM, hTf, srcp, dstp, maskp, Ab, nullptr, nullptr);
    gbar(bar, NBLK * 3);

    // ---- P3: gemm2 ----
    for (int vb = rb * 2 + hb; vb < 1280; vb += 1024)
        gemm_body<128, 1>(vb, t2, nullptr, Ab, WT2, b2, a2, srcp, dstp, hTf);
    gbar(bar, NBLK * 4);

    // ---- P4: agg2 ----
    agg_body<0>(rb, t, SM, hTf, srcp, dstp, maskp, Ab, nullptr, nullptr);
    gbar(bar, NBLK * 5);

    // ---- P5: gemm3 ----
    for (int vb = rb * 2 + hb; vb < 1280; vb += 1024)
        gemm_body<128, 1>(vb, t2, nullptr, Ab, WT3, b3, a3, srcp, dstp, hTf);
    gbar(bar, NBLK * 6);

    // ---- P6: agg3 + pooling ----
    agg_body<1>(rb, t, SM, hTf, srcp, dstp, maskp, nullptr, poolS, poolM);
    gbar(bar, NBLK * 7);

    // ---- P7: mlp1 ----
    if (rb < 80) mlp1_body(rb * 2 + hb, t2, (float*)(SM + hb * 1024), x, poolS, poolM, We1, z1p);
    gbar(bar, NBLK * 8);

    // ---- P8: mlp2 ----
    if (rb < 32) mlp2_body(rb, t, SM, z1p, be1, We2, be2, We3, be3, out);
}

// ---------------- workspace layout ----------------
constexpr size_t O_MASK  = 0;                            // 2,097,152
constexpr size_t O_SRCP  = 2097152;                      // 327,680
constexpr size_t O_DSTP  = O_SRCP + 327680;              // 327,680
constexpr size_t O_AB    = O_DSTP + 327680;              // 2,097,152
constexpr size_t O_HT    = O_AB + 2097152;               // 10,485,760
constexpr size_t O_WT1   = O_HT + 10485760;              // 81,920
constexpr size_t O_WT2   = O_WT1 + 81920;                // 163,840
constexpr size_t O_WT3   = O_WT2 + 163840;               // 163,840
constexpr size_t O_POOLS = O_WT3 + 163840;               // 262,144
constexpr size_t O_POOLM = O_POOLS + 262144;             // 262,144
constexpr size_t O_Z1P   = O_POOLM + 262144;             // 163,840
constexpr size_t O_BAR   = O_Z1P + 163840;               // 64

extern "C" void kernel_launch(void* const* d_in, const int* in_sizes, int n_in,
                              void* d_out, int out_size, void* d_ws, size_t ws_size,
                              hipStream_t stream) {
    const float* x       = (const float*)d_in[0];
    const float* y_atoms = (const float*)d_in[1];
    const int*   y_bonds = (const int*)d_in[2];
    const float* W1 = (const float*)d_in[3];
    const float* b1 = (const float*)d_in[4];
    const float* a1 = (const float*)d_in[5];
    const float* W2 = (const float*)d_in[6];
    const float* b2 = (const float*)d_in[7];
    const float* a2 = (const float*)d_in[8];
    const float* W3 = (const float*)d_in[9];
    const float* b3 = (const float*)d_in[10];
    const float* a3 = (const float*)d_in[11];
    const float* We1 = (const float*)d_in[12];
    const float* be1 = (const float*)d_in[13];
    const float* We2 = (const float*)d_in[14];
    const float* be2 = (const float*)d_in[15];
    const float* We3 = (const float*)d_in[16];
    const float* be3 = (const float*)d_in[17];
    float* out = (float*)d_out;

    char* ws = (char*)d_ws;
    unsigned char* maskp = (unsigned char*)(ws + O_MASK);
    float* srcp = (float*)(ws + O_SRCP);
    float* dstp = (float*)(ws + O_DSTP);
    unsigned short* Ab = (unsigned short*)(ws + O_AB);
    unsigned short* hTf = (unsigned short*)(ws + O_HT);
    unsigned short* WT1 = (unsigned short*)(ws + O_WT1);
    unsigned short* WT2 = (unsigned short*)(ws + O_WT2);
    unsigned short* WT3 = (unsigned short*)(ws + O_WT3);
    float* poolS = (float*)(ws + O_POOLS);
    float* poolM = (float*)(ws + O_POOLM);
    float* z1p   = (float*)(ws + O_Z1P);
    unsigned* bar = (unsigned*)(ws + O_BAR);

    hipMemsetAsync(bar, 0, 64, stream);
    k_mega<<<NBLK, 512, 0, stream>>>(
        x, y_atoms, y_bonds, W1, b1, a1, W2, b2, a2, W3, b3, a3,
        We1, be1, We2, be2, We3, be3,
        maskp, srcp, dstp, Ab, hTf, WT1, WT2, WT3, poolS, poolM, z1p, bar, out);
}

// Round 6
// 405.641 us; speedup vs baseline: 1.5659x; 1.5659x over previous
//
#include <hip/hip_runtime.h>
#include <cstddef>

#define NBLK 512
#define REL_N 16

typedef __attribute__((ext_vector_type(8))) short bf16x8;
typedef __attribute__((ext_vector_type(4))) float f32x4;

__device__ __forceinline__ float lrelu(float x) { return x >= 0.f ? x : 0.2f * x; }
// RNE float -> bf16
__device__ __forceinline__ unsigned short f2bf(float x) {
    unsigned u = __float_as_uint(x);
    u += 0x7FFFu + ((u >> 16) & 1u);
    return (unsigned short)(u >> 16);
}
__device__ __forceinline__ float bf2f(unsigned short u) {
    return __uint_as_float((unsigned)u << 16);
}

// ---------------------------------------------------------------------------------------
// Grid barrier, contention-shaped (round-5 post-mortem: single-line arrive+poll convoyed
// at the coherence point, ~60us/barrier). Structure:
//   - arrivals: 8 padded counters (128B apart), rb&7 -> <=64 RMWs/line, nobody polls them
//   - block 0: sole aggregator, sums the 8 counters (only poller on those lines)
//   - release: 16 padded words; block 0 stores phase; block rb polls word rb>>5 only
//     (32 pollers/line at ~0.7us cycle ~= 45 polls/us/line, under LLC single-line capacity)
// Counters/release are monotonic across phases (memset once per iteration, graph-ordered).
// Co-residency: __launch_bounds__(512,4) -> 16 waves/CU = 2 blocks/CU x 256 CU = 512;
// LDS 2x47KB < 160KB. Verified co-resident in round 5 (48% occupancy, no deadlock).
// ---------------------------------------------------------------------------------------
__device__ __forceinline__ void gbar(unsigned* barArr, unsigned* relArr,
                                     unsigned phase, int rb) {
    __syncthreads();
    if (threadIdx.x == 0) {
        __threadfence();
        __hip_atomic_fetch_add(&barArr[(rb & 7) * 32], 1u, __ATOMIC_RELAXED,
                               __HIP_MEMORY_SCOPE_AGENT);
        if (rb == 0) {
            const unsigned target = phase * NBLK;
            unsigned sum;
            do {
                __builtin_amdgcn_s_sleep(2);
                sum = 0;
#pragma unroll
                for (int i = 0; i < 8; ++i)
                    sum += __hip_atomic_load(&barArr[i * 32], __ATOMIC_RELAXED,
                                             __HIP_MEMORY_SCOPE_AGENT);
            } while (sum < target);
#pragma unroll
            for (int g = 0; g < REL_N; ++g)
                __hip_atomic_store(&relArr[g * 32], phase, __ATOMIC_RELAXED,
                                   __HIP_MEMORY_SCOPE_AGENT);
        } else {
            unsigned* myrel = &relArr[(rb >> 5) * 32];
            while (__hip_atomic_load(myrel, __ATOMIC_RELAXED,
                                     __HIP_MEMORY_SCOPE_AGENT) < phase)
                __builtin_amdgcn_s_sleep(16);
        }
        __threadfence();
    }
    __syncthreads();
}

// ---------------------------------------------------------------------------------------
// W (K x 640 fp32) -> WT (640 x K bf16), one 64-col n-tile, 512 threads.
// ---------------------------------------------------------------------------------------
__device__ __forceinline__ void wtrans(const float* __restrict__ W,
                                       unsigned short* __restrict__ WT,
                                       int K, int nt, int t) {
    int n = nt * 64 + (t & 63);
    for (int kg = t >> 6; kg < K / 8; kg += 8) {
        bf16x8 v;
#pragma unroll
        for (int e = 0; e < 8; ++e) v[e] = (short)f2bf(W[(size_t)(kg * 8 + e) * 640 + n]);
        *(bf16x8*)&WT[(size_t)n * K + kg * 8] = v;
    }
}

// pack y_bonds -> maskp: one uint (4 items x 5 r-bits) per call.
__device__ __forceinline__ void maskpack(const int* __restrict__ bonds,
                                         unsigned char* __restrict__ maskp, int gt) {
    const int4* p = (const int4*)(bonds + (size_t)gt * 20);
    int4 q0 = p[0], q1 = p[1], q2 = p[2], q3 = p[3], q4 = p[4];
    int v[20] = {q0.x, q0.y, q0.z, q0.w, q1.x, q1.y, q1.z, q1.w,
                 q2.x, q2.y, q2.z, q2.w, q3.x, q3.y, q3.z, q3.w,
                 q4.x, q4.y, q4.z, q4.w};
    unsigned m = 0;
#pragma unroll
    for (int k = 0; k < 4; ++k)
#pragma unroll
        for (int r = 0; r < 5; ++r)
            m |= (v[k * 5 + r] == 1) ? (1u << (k * 8 + r)) : 0u;
    *(unsigned*)&maskp[(size_t)gt * 4] = m;
}

// ---------------------------------------------------------------------------------------
// gemm body: virtual 256-thread block (t in [0,256)), barrier-free, so two run per real
// block (halves). Identical math/layout to the verified round-4 k_gemm_h, incl. the
// XCD-affinity swizzle l -> (mt, nt).
// ---------------------------------------------------------------------------------------
template <int K, int MODE>
__device__ __forceinline__ void gemm_body(int l, int t,
                                          const float* __restrict__ Af32,
                                          const unsigned short* __restrict__ Ab,
                                          const unsigned short* __restrict__ WTg,
                                          const float* __restrict__ bias,
                                          const float* __restrict__ avec,
                                          float* __restrict__ srcp,
                                          float* __restrict__ dstp,
                                          unsigned short* __restrict__ hTf) {
    const int mt = (l & 7) * 16 + ((l >> 3) & 15);   // [0,128)
    const int nt = l >> 7;                            // [0,10)
    const int n0 = nt * 64, m0 = mt * 64;
    const int w = t >> 6, lane = t & 63;
    const int colg = lane & 15, rquad = lane >> 4;
    const int m = m0 + w * 16 + colg;
    const int koff = rquad * 8;

    f32x4 acc[4] = {};
#pragma unroll
    for (int kk = 0; kk < K; kk += 32) {
        bf16x8 af;
        size_t off = (size_t)m * K + kk + koff;
        if (MODE == 1) {
            af = *(const bf16x8*)&Ab[off];
        } else {
            float4 q0 = *(const float4*)&Af32[off];
            float4 q1 = *(const float4*)&Af32[off + 4];
            af[0] = (short)f2bf(q0.x); af[1] = (short)f2bf(q0.y);
            af[2] = (short)f2bf(q0.z); af[3] = (short)f2bf(q0.w);
            af[4] = (short)f2bf(q1.x); af[5] = (short)f2bf(q1.y);
            af[6] = (short)f2bf(q1.z); af[7] = (short)f2bf(q1.w);
        }
#pragma unroll
        for (int ct = 0; ct < 4; ++ct) {
            bf16x8 bfv = *(const bf16x8*)&WTg[(size_t)(n0 + ct * 16 + colg) * K + kk + koff];
            acc[ct] = __builtin_amdgcn_mfma_f32_16x16x32_bf16(af, bfv, acc[ct], 0, 0, 0);
        }
    }

    const int r = n0 >> 7, chalf = n0 & 127;
    const int b = m0 >> 8, jb = m0 & 255;
    float val[4][4];
    float ssum[4] = {0.f, 0.f, 0.f, 0.f}, dsum[4] = {0.f, 0.f, 0.f, 0.f};
#pragma unroll
    for (int ct = 0; ct < 4; ++ct) {
        int cg = chalf + ct * 16 + colg;
        float bv = bias[n0 + ct * 16 + colg];
        float asr = avec[r * 256 + cg];
        float ads = avec[r * 256 + 128 + cg];
#pragma unroll
        for (int reg = 0; reg < 4; ++reg) {
            float v = acc[ct][reg] + bv;
            val[ct][reg] = v;
            ssum[reg] += v * asr;
            dsum[reg] += v * ads;
        }
    }
#pragma unroll
    for (int mk = 1; mk < 16; mk <<= 1)
#pragma unroll
        for (int reg = 0; reg < 4; ++reg) {
            ssum[reg] += __shfl_xor(ssum[reg], mk);
            dsum[reg] += __shfl_xor(dsum[reg], mk);
        }
    if (colg == 0) {
        int nhalf = (n0 >> 6) & 1;
#pragma unroll
        for (int reg = 0; reg < 4; ++reg) {
            int row = m0 + w * 16 + rquad * 4 + reg;
            srcp[nhalf * 40960 + row * 5 + r] = ssum[reg];
            dstp[nhalf * 40960 + row * 5 + r] = dsum[reg];
        }
    }
    {
        const int joct = (jb >> 3) + w * 2 + (rquad >> 1);
        const size_t tile = (size_t)((b * 5 + r) * 32 + joct) * 1024;
        const int sub = (rquad & 1) * 4;
#pragma unroll
        for (int ct = 0; ct < 4; ++ct) {
            int c = chalf + ct * 16 + colg;
            uint2 pk;
            pk.x = (unsigned)f2bf(val[ct][0]) | ((unsigned)f2bf(val[ct][1]) << 16);
            pk.y = (unsigned)f2bf(val[ct][2]) | ((unsigned)f2bf(val[ct][3]) << 16);
            *(uint2*)&hTf[tile + (size_t)c * 8 + sub] = pk;
        }
    }
}

// ---------------------------------------------------------------------------------------
// agg body: 512 threads, 1:1 with a real block (l = rb), identical to verified round-4
// k_agg incl. XCD-affinity swizzle. LDS passed in (shared union across phases).
// ---------------------------------------------------------------------------------------
template <int FINAL>
__device__ __forceinline__ void agg_body(int l, int t, unsigned char* SM,
                                         const unsigned short* __restrict__ hTf,
                                         const float* __restrict__ srcp,
                                         const float* __restrict__ dstp,
                                         const unsigned char* __restrict__ maskp,
                                         unsigned short* __restrict__ Ab,
                                         float* __restrict__ poolS,
                                         float* __restrict__ poolM) {
    unsigned short* Ps = (unsigned short*)SM;         // 40960 B
    float* Ds2l = (float*)(SM + 40960);               // 5120 B
    float* Ss   = (float*)(SM + 46080);               // 320 B
    float* Zw   = (float*)(SM + 46400);               // 512 B
    float* Zrow = (float*)(SM + 46912);               // 64 B

    const int b = (l & 7) * 4 + ((l >> 3) & 3);       // [0,32), XCD(b)=b/4
    const int itile = l >> 5;                          // [0,16)
    const int ib = b * 256 + itile * 16;
    const int w = t >> 6, lane = t & 63;
    const int colg = lane & 15, rquad = lane >> 4;
    const int c = w * 16 + colg;
    const size_t bbase = (size_t)(b * 5) * 32 * 1024;

    if (t < 80) Ss[t] = srcp[(size_t)ib * 5 + t] + srcp[40960 + (size_t)ib * 5 + t];
    for (int idx = t; idx < 1280; idx += 512) {
        int jl = idx & 255, rr = idx >> 8;
        size_t o = (size_t)(b * 256 + jl) * 5 + rr;
        Ds2l[rr * 256 + jl] = dstp[o] + dstp[40960 + o];
    }
    bf16x8 pre[4];
#pragma unroll
    for (int s = 0; s < 4; ++s)
        pre[s] = *(const bf16x8*)&hTf[bbase + (size_t)(s * 4 + rquad) * 1024 + (size_t)c * 8];
    __syncthreads();

    {
        const int i = t & 15;
        const int kq = (t >> 4) & 3;
        float esum = 0.f;
#pragma unroll
        for (int it = 0; it < 5; ++it) {
            int p = it * 512 + t;
            int s = p >> 6;
            int k0 = s * 32 + kq * 8;
            int rr = k0 >> 8, j0 = k0 & 255;
            uint2 mk8 = *(const uint2*)&maskp[((size_t)(ib + i) << 8) + j0];
            float sv = Ss[i * 5 + rr];
            float4 d0 = *(const float4*)&Ds2l[rr * 256 + j0];
            float4 d1 = *(const float4*)&Ds2l[rr * 256 + j0 + 4];
            float dv[8] = {d0.x, d0.y, d0.z, d0.w, d1.x, d1.y, d1.z, d1.w};
            bf16x8 pv;
#pragma unroll
            for (int e = 0; e < 8; ++e) {
                unsigned mb = ((e < 4 ? (mk8.x >> (8 * e)) : (mk8.y >> (8 * (e - 4)))) >> rr) & 1u;
                float vv = lrelu(sv + dv[e]);
                float ev = mb ? __expf(vv) : 0.f;
                unsigned short q = f2bf(ev);
                pv[e] = (short)q;
                esum += __uint_as_float((unsigned)q << 16);
            }
            *(bf16x8*)&Ps[p * 8] = pv;
        }
        esum += __shfl_xor(esum, 16);
        esum += __shfl_xor(esum, 32);
        if (lane < 16) Zw[w * 16 + (lane & 15)] = esum;
    }
    __syncthreads();
    if (t < 16) {
        float z = 0.f;
#pragma unroll
        for (int ww = 0; ww < 8; ++ww) z += Zw[ww * 16 + t];
        Zrow[t] = 1.f / z;
    }

    f32x4 acc0 = {}, acc1 = {};
#pragma unroll
    for (int s = 0; s < 8; ++s) {
        bf16x8 af = *(const bf16x8*)&Ps[(s * 64 + lane) * 8];
        bf16x8 bfv;
        if (s < 4) bfv = pre[s];
        else bfv = *(const bf16x8*)&hTf[bbase + (size_t)((s & 7) * 4 + rquad) * 1024 + (size_t)c * 8];
        if (s & 1) acc1 = __builtin_amdgcn_mfma_f32_16x16x32_bf16(af, bfv, acc1, 0, 0, 0);
        else       acc0 = __builtin_amdgcn_mfma_f32_16x16x32_bf16(af, bfv, acc0, 0, 0, 0);
    }
#pragma unroll 8
    for (int s = 8; s < 40; ++s) {
        bf16x8 af = *(const bf16x8*)&Ps[(s * 64 + lane) * 8];
        bf16x8 bfv = *(const bf16x8*)&hTf[bbase +
            (size_t)((s >> 3) * 32 + (s & 7) * 4 + rquad) * 1024 + (size_t)c * 8];
        if (s & 1) acc1 = __builtin_amdgcn_mfma_f32_16x16x32_bf16(af, bfv, acc1, 0, 0, 0);
        else       acc0 = __builtin_amdgcn_mfma_f32_16x16x32_bf16(af, bfv, acc0, 0, 0, 0);
    }
    __syncthreads();
    const int irow = ib + rquad * 4;
    if (FINAL) {
        float ps = 0.f, pm = -3.4e38f;
#pragma unroll
        for (int reg = 0; reg < 4; ++reg) {
            float v = (acc0[reg] + acc1[reg]) * Zrow[rquad * 4 + reg];
            ps += v;
            pm = fmaxf(pm, v);
        }
        ps += __shfl_xor(ps, 16);
        ps += __shfl_xor(ps, 32);
        pm = fmaxf(pm, __shfl_xor(pm, 16));
        pm = fmaxf(pm, __shfl_xor(pm, 32));
        if (rquad == 0) {
            poolS[(size_t)(b * 16 + itile) * 128 + c] = ps;
            poolM[(size_t)(b * 16 + itile) * 128 + c] = pm;
        }
    } else {
#pragma unroll
        for (int reg = 0; reg < 4; ++reg) {
            float v = (acc0[reg] + acc1[reg]) * Zrow[rquad * 4 + reg];
            Ab[(size_t)(irow + reg) * 128 + c] = f2bf(lrelu(v));
        }
    }
}

// ---------------------------------------------------------------------------------------
// mlp1 partials: ALL 512 blocks. rb -> (b = rb>>4, kc = rb&15); k-range [kc*80, kc*80+80)
// of z = [x(1024) | mean(128) | max(128)]. Thread t: o = t&255, half = t>>8 (40 k each).
// Per block: 80 KB of We1, coalesced rows. XCD(rb)=rb%8=kc%8 -> the 32 b-blocks of a
// kc-chunk share their We1 rows in one XCD's L2.
// ---------------------------------------------------------------------------------------
__device__ __forceinline__ void mlp1p(int rb, int t, float* zs,
                                      const float* __restrict__ x,
                                      const float* __restrict__ poolS,
                                      const float* __restrict__ poolM,
                                      const float* __restrict__ We1,
                                      float* __restrict__ z1p) {
    const int b = rb >> 4, kc = rb & 15;
    if (t < 80) {
        int k = kc * 80 + t;
        float v;
        if (k < 1024) {
            v = x[(size_t)b * 1024 + k];
        } else if (k < 1152) {
            int f = k - 1024;
            float s = 0.f;
#pragma unroll
            for (int it = 0; it < 16; ++it) s += poolS[(size_t)(b * 16 + it) * 128 + f];
            v = s * (1.f / 256.f);
        } else {
            int f = k - 1152;
            float mx = -3.4e38f;
#pragma unroll
            for (int it = 0; it < 16; ++it) mx = fmaxf(mx, poolM[(size_t)(b * 16 + it) * 128 + f]);
            v = mx;
        }
        zs[t] = v;
    }
    __syncthreads();
    const int o = t & 255, half = t >> 8;
    float s = 0.f;
#pragma unroll 8
    for (int kk = 0; kk < 40; ++kk)
        s += zs[half * 40 + kk] * We1[(size_t)(kc * 80 + half * 40 + kk) * 256 + o];
    z1p[(size_t)rb * 512 + half * 256 + o] = s;
}

// mlp2 body: 512 threads, b = rb; combine 32 z1 partials; mlp2 k-split; mlp3.
__device__ __forceinline__ void mlp2_body(int b, int t, unsigned char* SM,
                                          const float* __restrict__ z1p,
                                          const float* __restrict__ be1,
                                          const float* __restrict__ We2,
                                          const float* __restrict__ be2,
                                          const float* __restrict__ We3,
                                          const float* __restrict__ be3,
                                          float* __restrict__ out) {
    float* z1s = (float*)SM;              // 1024 B
    float* s2p = (float*)(SM + 1024);     // 1024 B
    float* z2s = (float*)(SM + 2048);     // 128 B
    if (t < 256) {
        float s = be1[t];
#pragma unroll
        for (int kc = 0; kc < 16; ++kc) {
            size_t base = (size_t)(b * 16 + kc) * 512;
            s += z1p[base + t] + z1p[base + 256 + t];
        }
        z1s[t] = lrelu(s);
    }
    __syncthreads();
    if (t < 256) {
        int o = t & 31, g = t >> 5;
        float p = 0.f;
#pragma unroll
        for (int k = 0; k < 32; ++k) p += z1s[g * 32 + k] * We2[(g * 32 + k) * 32 + o];
        s2p[g * 32 + o] = p;
    }
    __syncthreads();
    if (t < 32) {
        float s2 = be2[t];
#pragma unroll
        for (int g = 0; g < 8; ++g) s2 += s2p[g * 32 + t];
        z2s[t] = lrelu(s2);
    }
    __syncthreads();
    if (t == 0) {
        float s3 = be3[0];
#pragma unroll
        for (int k = 0; k < 32; ++k) s3 += z2s[k] * We3[k];
        out[b] = s3;
    }
}

// =======================================================================================
// Persistent mega-kernel: 512 blocks x 512 threads, 9 phases, 8 grid barriers.
// P0: WT1            P1: gemm1 || maskpack || WT2/WT3     P2: agg1
// P3: gemm2          P4: agg2          P5: gemm3          P6: agg3(pool)
// P7: mlp1 partials (all 512)          P8: mlp2 (32 blocks)
// =======================================================================================
__global__ __launch_bounds__(512, 4) void k_mega(
    const float* __restrict__ x, const float* __restrict__ y_atoms,
    const int* __restrict__ bonds,
    const float* __restrict__ W1, const float* __restrict__ b1, const float* __restrict__ a1,
    const float* __restrict__ W2, const float* __restrict__ b2, const float* __restrict__ a2,
    const float* __restrict__ W3, const float* __restrict__ b3, const float* __restrict__ a3,
    const float* __restrict__ We1, const float* __restrict__ be1,
    const float* __restrict__ We2, const float* __restrict__ be2,
    const float* __restrict__ We3, const float* __restrict__ be3,
    unsigned char* __restrict__ maskp, float* __restrict__ srcp, float* __restrict__ dstp,
    unsigned short* __restrict__ Ab, unsigned short* __restrict__ hTf,
    unsigned short* __restrict__ WT1, unsigned short* __restrict__ WT2,
    unsigned short* __restrict__ WT3,
    float* __restrict__ poolS, float* __restrict__ poolM, float* __restrict__ z1p,
    unsigned* barArr, unsigned* relArr, float* __restrict__ out) {
    __shared__ __align__(16) unsigned char SM[46976];
    const int rb = blockIdx.x;
    const int t = threadIdx.x;
    const int hb = t >> 8, t2 = t & 255;

    // ---- P0: WT1 ----
    if (rb < 10) wtrans(W1, WT1, 64, rb, t);
    gbar(barArr, relArr, 1, rb);

    // ---- P1: gemm1 + mask pack + WT2/WT3 ----
    for (int vb = rb * 2 + hb; vb < 1280; vb += 1024)
        gemm_body<64, 0>(vb, t2, y_atoms, nullptr, WT1, b1, a1, srcp, dstp, hTf);
    if (rb >= 480 && rb < 490)      wtrans(W2, WT2, 128, rb - 480, t);
    else if (rb >= 490 && rb < 500) wtrans(W3, WT3, 128, rb - 490, t);
    {
        int gt = rb * 512 + t;
        maskpack(bonds, maskp, gt);
        maskpack(bonds, maskp, gt + 262144);
    }
    gbar(barArr, relArr, 2, rb);

    // ---- P2: agg1 ----
    agg_body<0>(rb, t, SM, hTf, srcp, dstp, maskp, Ab, nullptr, nullptr);
    gbar(barArr, relArr, 3, rb);

    // ---- P3: gemm2 ----
    for (int vb = rb * 2 + hb; vb < 1280; vb += 1024)
        gemm_body<128, 1>(vb, t2, nullptr, Ab, WT2, b2, a2, srcp, dstp, hTf);
    gbar(barArr, relArr, 4, rb);

    // ---- P4: agg2 ----
    agg_body<0>(rb, t, SM, hTf, srcp, dstp, maskp, Ab, nullptr, nullptr);
    gbar(barArr, relArr, 5, rb);

    // ---- P5: gemm3 ----
    for (int vb = rb * 2 + hb; vb < 1280; vb += 1024)
        gemm_body<128, 1>(vb, t2, nullptr, Ab, WT3, b3, a3, srcp, dstp, hTf);
    gbar(barArr, relArr, 6, rb);

    // ---- P6: agg3 + pooling ----
    agg_body<1>(rb, t, SM, hTf, srcp, dstp, maskp, nullptr, poolS, poolM);
    gbar(barArr, relArr, 7, rb);

    // ---- P7: mlp1 partials (all 512 blocks) ----
    mlp1p(rb, t, (float*)SM, x, poolS, poolM, We1, z1p);
    gbar(barArr, relArr, 8, rb);

    // ---- P8: mlp2 ----
    if (rb < 32) mlp2_body(rb, t, SM, z1p, be1, We2, be2, We3, be3, out);
}

// ---------------- workspace layout ----------------
constexpr size_t O_MASK  = 0;                            // 2,097,152
constexpr size_t O_SRCP  = 2097152;                      // 327,680
constexpr size_t O_DSTP  = O_SRCP + 327680;              // 327,680
constexpr size_t O_AB    = O_DSTP + 327680;              // 2,097,152
constexpr size_t O_HT    = O_AB + 2097152;               // 10,485,760
constexpr size_t O_WT1   = O_HT + 10485760;              // 81,920
constexpr size_t O_WT2   = O_WT1 + 81920;                // 163,840
constexpr size_t O_WT3   = O_WT2 + 163840;               // 163,840
constexpr size_t O_POOLS = O_WT3 + 163840;               // 262,144
constexpr size_t O_POOLM = O_POOLS + 262144;             // 262,144
constexpr size_t O_Z1P   = O_POOLM + 262144;             // 1,048,576
constexpr size_t O_BAR   = O_Z1P + 1048576;              // 1,024 (8 x 128B counters)
constexpr size_t O_REL   = O_BAR + 1024;                 // 2,048 (16 x 128B release)

extern "C" void kernel_launch(void* const* d_in, const int* in_sizes, int n_in,
                              void* d_out, int out_size, void* d_ws, size_t ws_size,
                              hipStream_t stream) {
    const float* x       = (const float*)d_in[0];
    const float* y_atoms = (const float*)d_in[1];
    const int*   y_bonds = (const int*)d_in[2];
    const float* W1 = (const float*)d_in[3];
    const float* b1 = (const float*)d_in[4];
    const float* a1 = (const float*)d_in[5];
    const float* W2 = (const float*)d_in[6];
    const float* b2 = (const float*)d_in[7];
    const float* a2 = (const float*)d_in[8];
    const float* W3 = (const float*)d_in[9];
    const float* b3 = (const float*)d_in[10];
    const float* a3 = (const float*)d_in[11];
    const float* We1 = (const float*)d_in[12];
    const float* be1 = (const float*)d_in[13];
    const float* We2 = (const float*)d_in[14];
    const float* be2 = (const float*)d_in[15];
    const float* We3 = (const float*)d_in[16];
    const float* be3 = (const float*)d_in[17];
    float* out = (float*)d_out;

    char* ws = (char*)d_ws;
    unsigned char* maskp = (unsigned char*)(ws + O_MASK);
    float* srcp = (float*)(ws + O_SRCP);
    float* dstp = (float*)(ws + O_DSTP);
    unsigned short* Ab = (unsigned short*)(ws + O_AB);
    unsigned short* hTf = (unsigned short*)(ws + O_HT);
    unsigned short* WT1 = (unsigned short*)(ws + O_WT1);
    unsigned short* WT2 = (unsigned short*)(ws + O_WT2);
    unsigned short* WT3 = (unsigned short*)(ws + O_WT3);
    float* poolS = (float*)(ws + O_POOLS);
    float* poolM = (float*)(ws + O_POOLM);
    float* z1p   = (float*)(ws + O_Z1P);
    unsigned* barArr = (unsigned*)(ws + O_BAR);
    unsigned* relArr = (unsigned*)(ws + O_REL);

    hipMemsetAsync(barArr, 0, 3072, stream);
    k_mega<<<NBLK, 512, 0, stream>>>(
        x, y_atoms, y_bonds, W1, b1, a1, W2, b2, a2, W3, b3, a3,
        We1, be1, We2, be2, We3, be3,
        maskp, srcp, dstp, Ab, hTf, WT1, WT2, WT3, poolS, poolM, z1p,
        barArr, relArr, out);
}

// Round 7
// 219.230 us; speedup vs baseline: 2.8973x; 1.8503x over previous
//
#include <hip/hip_runtime.h>
#include <cstddef>

#define NBLK 512

typedef __attribute__((ext_vector_type(8))) short bf16x8;
typedef __attribute__((ext_vector_type(4))) float f32x4;

__device__ __forceinline__ float lrelu(float x) { return x >= 0.f ? x : 0.2f * x; }
__device__ __forceinline__ unsigned short f2bf(float x) {
    unsigned u = __float_as_uint(x);
    u += 0x7FFFu + ((u >> 16) & 1u);
    return (unsigned short)(u >> 16);
}
__device__ __forceinline__ float bf2f(unsigned short u) {
    return __uint_as_float((unsigned)u << 16);
}

// ---------------- sync area (uint indices into sync[]) ----------------
// SY_CNT: 8 lines  - per-XCD registration counters
// SY_GA : 8 lines  - global rendezvous arrivals (split by rb&7)
// SY_GR : 16 lines - global rendezvous release
// SY_XB : 64 lines - per-XCD barrier arrivals, (xcd*8 + (r&7))
// SY_XR : 16 lines - per-XCD release, (xcd*2 + (r&1))
#define SY_CNT 0
#define SY_GA  256
#define SY_GR  512
#define SY_XB  1024
#define SY_XR  3072

// ---------------------------------------------------------------------------------------
// Per-XCD barrier: NO cache fences (round-6 post-mortem: __threadfence = buffer_wbl2 +
// buffer_inv x 512 blocks = ~33us/barrier). Correctness without fences:
//  - CDNA vector L1 is write-through; __syncthreads drains vmcnt -> stores are in the
//    XCD-shared L2 before the arrival atomic issues.
//  - all producer/consumer pairs are on the SAME XCD (XCD-closed dataflow), so L2
//    visibility suffices; LLC/agent atomics used only for the barrier words themselves.
//  - L1 staleness is eliminated structurally: every cross-block address is read in
//    exactly ONE phase (hTf x3, Ab x2, src/dst x3 multi-buffering; maskp immutable).
// Arrivals split over 8 lines per XCD; rank-0 aggregates; 2 release lines per XCD
// (~cnt/2 = 32 pollers/line @ s_sleep(16)).
// ---------------------------------------------------------------------------------------
__device__ __forceinline__ void xbar(unsigned* sync, int xcd, int r, unsigned cnt,
                                     unsigned ph, int t) {
    __syncthreads();
    if (t == 0) {
        __hip_atomic_fetch_add(&sync[SY_XB + (xcd * 8 + (r & 7)) * 32], 1u,
                               __ATOMIC_RELAXED, __HIP_MEMORY_SCOPE_AGENT);
        if (r == 0) {
            const unsigned tgt = cnt * ph;
            unsigned s;
            do {
                __builtin_amdgcn_s_sleep(2);
                s = 0;
#pragma unroll
                for (int i = 0; i < 8; ++i)
                    s += __hip_atomic_load(&sync[SY_XB + (xcd * 8 + i) * 32],
                                           __ATOMIC_RELAXED, __HIP_MEMORY_SCOPE_AGENT);
            } while (s < tgt);
            __hip_atomic_store(&sync[SY_XR + (xcd * 2 + 0) * 32], ph,
                               __ATOMIC_RELAXED, __HIP_MEMORY_SCOPE_AGENT);
            __hip_atomic_store(&sync[SY_XR + (xcd * 2 + 1) * 32], ph,
                               __ATOMIC_RELAXED, __HIP_MEMORY_SCOPE_AGENT);
        } else {
            unsigned* w = &sync[SY_XR + (xcd * 2 + (r & 1)) * 32];
            while (__hip_atomic_load(w, __ATOMIC_RELAXED, __HIP_MEMORY_SCOPE_AGENT) < ph)
                __builtin_amdgcn_s_sleep(16);
        }
    }
    __syncthreads();
}

// W (K x 640 fp32) -> WT (640 x K bf16), one 64-col n-tile, 512 threads.
__device__ __forceinline__ void wtrans(const float* __restrict__ W,
                                       unsigned short* __restrict__ WT,
                                       int K, int nt, int t) {
    int n = nt * 64 + (t & 63);
    for (int kg = t >> 6; kg < K / 8; kg += 8) {
        bf16x8 v;
#pragma unroll
        for (int e = 0; e < 8; ++e) v[e] = (short)f2bf(W[(size_t)(kg * 8 + e) * 640 + n]);
        *(bf16x8*)&WT[(size_t)n * K + kg * 8] = v;
    }
}

// pack y_bonds -> maskp: one uint (4 items x 5 r-bits) per call.
__device__ __forceinline__ void maskpack(const int* __restrict__ bonds,
                                         unsigned char* __restrict__ maskp, int gt) {
    const int4* p = (const int4*)(bonds + (size_t)gt * 20);
    int4 q0 = p[0], q1 = p[1], q2 = p[2], q3 = p[3], q4 = p[4];
    int v[20] = {q0.x, q0.y, q0.z, q0.w, q1.x, q1.y, q1.z, q1.w,
                 q2.x, q2.y, q2.z, q2.w, q3.x, q3.y, q3.z, q3.w,
                 q4.x, q4.y, q4.z, q4.w};
    unsigned m = 0;
#pragma unroll
    for (int k = 0; k < 4; ++k)
#pragma unroll
        for (int r = 0; r < 5; ++r)
            m |= (v[k * 5 + r] == 1) ? (1u << (k * 8 + r)) : 0u;
    *(unsigned*)&maskp[(size_t)gt * 4] = m;
}

// ---------------------------------------------------------------------------------------
// gemm body: one (mt, nt) tile, virtual 256-thread block (t in [0,256)), barrier-free.
// Math identical to the verified round-4 k_gemm_h.
// ---------------------------------------------------------------------------------------
template <int K, int MODE>
__device__ __forceinline__ void gemm_body(int mt, int nt, int t,
                                          const float* __restrict__ Af32,
                                          const unsigned short* __restrict__ Ab,
                                          const unsigned short* __restrict__ WTg,
                                          const float* __restrict__ bias,
                                          const float* __restrict__ avec,
                                          float* __restrict__ srcp,
                                          float* __restrict__ dstp,
                                          unsigned short* __restrict__ hTf) {
    const int n0 = nt * 64, m0 = mt * 64;
    const int w = t >> 6, lane = t & 63;
    const int colg = lane & 15, rquad = lane >> 4;
    const int m = m0 + w * 16 + colg;
    const int koff = rquad * 8;

    f32x4 acc[4] = {};
#pragma unroll
    for (int kk = 0; kk < K; kk += 32) {
        bf16x8 af;
        size_t off = (size_t)m * K + kk + koff;
        if (MODE == 1) {
            af = *(const bf16x8*)&Ab[off];
        } else {
            float4 q0 = *(const float4*)&Af32[off];
            float4 q1 = *(const float4*)&Af32[off + 4];
            af[0] = (short)f2bf(q0.x); af[1] = (short)f2bf(q0.y);
            af[2] = (short)f2bf(q0.z); af[3] = (short)f2bf(q0.w);
            af[4] = (short)f2bf(q1.x); af[5] = (short)f2bf(q1.y);
            af[6] = (short)f2bf(q1.z); af[7] = (short)f2bf(q1.w);
        }
#pragma unroll
        for (int ct = 0; ct < 4; ++ct) {
            bf16x8 bfv = *(const bf16x8*)&WTg[(size_t)(n0 + ct * 16 + colg) * K + kk + koff];
            acc[ct] = __builtin_amdgcn_mfma_f32_16x16x32_bf16(af, bfv, acc[ct], 0, 0, 0);
        }
    }

    const int r = n0 >> 7, chalf = n0 & 127;
    const int b = m0 >> 8, jb = m0 & 255;
    float val[4][4];
    float ssum[4] = {0.f, 0.f, 0.f, 0.f}, dsum[4] = {0.f, 0.f, 0.f, 0.f};
#pragma unroll
    for (int ct = 0; ct < 4; ++ct) {
        int cg = chalf + ct * 16 + colg;
        float bv = bias[n0 + ct * 16 + colg];
        float asr = avec[r * 256 + cg];
        float ads = avec[r * 256 + 128 + cg];
#pragma unroll
        for (int reg = 0; reg < 4; ++reg) {
            float v = acc[ct][reg] + bv;
            val[ct][reg] = v;
            ssum[reg] += v * asr;
            dsum[reg] += v * ads;
        }
    }
#pragma unroll
    for (int mk = 1; mk < 16; mk <<= 1)
#pragma unroll
        for (int reg = 0; reg < 4; ++reg) {
            ssum[reg] += __shfl_xor(ssum[reg], mk);
            dsum[reg] += __shfl_xor(dsum[reg], mk);
        }
    if (colg == 0) {
        int nhalf = (n0 >> 6) & 1;
#pragma unroll
        for (int reg = 0; reg < 4; ++reg) {
            int row = m0 + w * 16 + rquad * 4 + reg;
            srcp[nhalf * 40960 + row * 5 + r] = ssum[reg];
            dstp[nhalf * 40960 + row * 5 + r] = dsum[reg];
        }
    }
    {
        const int joct = (jb >> 3) + w * 2 + (rquad >> 1);
        const size_t tile = (size_t)((b * 5 + r) * 32 + joct) * 1024;
        const int sub = (rquad & 1) * 4;
#pragma unroll
        for (int ct = 0; ct < 4; ++ct) {
            int c = chalf + ct * 16 + colg;
            uint2 pk;
            pk.x = (unsigned)f2bf(val[ct][0]) | ((unsigned)f2bf(val[ct][1]) << 16);
            pk.y = (unsigned)f2bf(val[ct][2]) | ((unsigned)f2bf(val[ct][3]) << 16);
            *(uint2*)&hTf[tile + (size_t)c * 8 + sub] = pk;
        }
    }
}

// ---------------------------------------------------------------------------------------
// agg body: one (b, itile) unit, 512 threads. Math identical to verified round-4 k_agg.
// ---------------------------------------------------------------------------------------
template <int FINAL>
__device__ __forceinline__ void agg_body(int b, int itile, int t, unsigned char* SM,
                                         const unsigned short* __restrict__ hTf,
                                         const float* __restrict__ srcp,
                                         const float* __restrict__ dstp,
                                         const unsigned char* __restrict__ maskp,
                                         unsigned short* __restrict__ Ab,
                                         float* __restrict__ poolS,
                                         float* __restrict__ poolM) {
    unsigned short* Ps = (unsigned short*)SM;         // 40960 B
    float* Ds2l = (float*)(SM + 40960);               // 5120 B
    float* Ss   = (float*)(SM + 46080);               // 320 B
    float* Zw   = (float*)(SM + 46400);               // 512 B
    float* Zrow = (float*)(SM + 46912);               // 64 B

    const int ib = b * 256 + itile * 16;
    const int w = t >> 6, lane = t & 63;
    const int colg = lane & 15, rquad = lane >> 4;
    const int c = w * 16 + colg;
    const size_t bbase = (size_t)(b * 5) * 32 * 1024;

    if (t < 80) Ss[t] = srcp[(size_t)ib * 5 + t] + srcp[40960 + (size_t)ib * 5 + t];
    for (int idx = t; idx < 1280; idx += 512) {
        int jl = idx & 255, rr = idx >> 8;
        size_t o = (size_t)(b * 256 + jl) * 5 + rr;
        Ds2l[rr * 256 + jl] = dstp[o] + dstp[40960 + o];
    }
    bf16x8 pre[4];
#pragma unroll
    for (int s = 0; s < 4; ++s)
        pre[s] = *(const bf16x8*)&hTf[bbase + (size_t)(s * 4 + rquad) * 1024 + (size_t)c * 8];
    __syncthreads();

    {
        const int i = t & 15;
        const int kq = (t >> 4) & 3;
        float esum = 0.f;
#pragma unroll
        for (int it = 0; it < 5; ++it) {
            int p = it * 512 + t;
            int s = p >> 6;
            int k0 = s * 32 + kq * 8;
            int rr = k0 >> 8, j0 = k0 & 255;
            uint2 mk8 = *(const uint2*)&maskp[((size_t)(ib + i) << 8) + j0];
            float sv = Ss[i * 5 + rr];
            float4 d0 = *(const float4*)&Ds2l[rr * 256 + j0];
            float4 d1 = *(const float4*)&Ds2l[rr * 256 + j0 + 4];
            float dv[8] = {d0.x, d0.y, d0.z, d0.w, d1.x, d1.y, d1.z, d1.w};
            bf16x8 pv;
#pragma unroll
            for (int e = 0; e < 8; ++e) {
                unsigned mb = ((e < 4 ? (mk8.x >> (8 * e)) : (mk8.y >> (8 * (e - 4)))) >> rr) & 1u;
                float vv = lrelu(sv + dv[e]);
                float ev = mb ? __expf(vv) : 0.f;
                unsigned short q = f2bf(ev);
                pv[e] = (short)q;
                esum += __uint_as_float((unsigned)q << 16);
            }
            *(bf16x8*)&Ps[p * 8] = pv;
        }
        esum += __shfl_xor(esum, 16);
        esum += __shfl_xor(esum, 32);
        if (lane < 16) Zw[w * 16 + (lane & 15)] = esum;
    }
    __syncthreads();
    if (t < 16) {
        float z = 0.f;
#pragma unroll
        for (int ww = 0; ww < 8; ++ww) z += Zw[ww * 16 + t];
        Zrow[t] = 1.f / z;
    }

    f32x4 acc0 = {}, acc1 = {};
#pragma unroll
    for (int s = 0; s < 8; ++s) {
        bf16x8 af = *(const bf16x8*)&Ps[(s * 64 + lane) * 8];
        bf16x8 bfv;
        if (s < 4) bfv = pre[s];
        else bfv = *(const bf16x8*)&hTf[bbase + (size_t)((s & 7) * 4 + rquad) * 1024 + (size_t)c * 8];
        if (s & 1) acc1 = __builtin_amdgcn_mfma_f32_16x16x32_bf16(af, bfv, acc1, 0, 0, 0);
        else       acc0 = __builtin_amdgcn_mfma_f32_16x16x32_bf16(af, bfv, acc0, 0, 0, 0);
    }
#pragma unroll 8
    for (int s = 8; s < 40; ++s) {
        bf16x8 af = *(const bf16x8*)&Ps[(s * 64 + lane) * 8];
        bf16x8 bfv = *(const bf16x8*)&hTf[bbase +
            (size_t)((s >> 3) * 32 + (s & 7) * 4 + rquad) * 1024 + (size_t)c * 8];
        if (s & 1) acc1 = __builtin_amdgcn_mfma_f32_16x16x32_bf16(af, bfv, acc1, 0, 0, 0);
        else       acc0 = __builtin_amdgcn_mfma_f32_16x16x32_bf16(af, bfv, acc0, 0, 0, 0);
    }
    __syncthreads();
    const int irow = ib + rquad * 4;
    if (FINAL) {
        float ps = 0.f, pm = -3.4e38f;
#pragma unroll
        for (int reg = 0; reg < 4; ++reg) {
            float v = (acc0[reg] + acc1[reg]) * Zrow[rquad * 4 + reg];
            ps += v;
            pm = fmaxf(pm, v);
        }
        ps += __shfl_xor(ps, 16);
        ps += __shfl_xor(ps, 32);
        pm = fmaxf(pm, __shfl_xor(pm, 16));
        pm = fmaxf(pm, __shfl_xor(pm, 32));
        if (rquad == 0) {
            poolS[(size_t)(b * 16 + itile) * 128 + c] = ps;
            poolM[(size_t)(b * 16 + itile) * 128 + c] = pm;
        }
    } else {
#pragma unroll
        for (int reg = 0; reg < 4; ++reg) {
            float v = (acc0[reg] + acc1[reg]) * Zrow[rquad * 4 + reg];
            Ab[(size_t)(irow + reg) * 128 + c] = f2bf(lrelu(v));
        }
    }
}

// mlp1 unit (b, kc): 512 threads; k-range [kc*80, kc*80+80) of z = [x | mean | max].
__device__ __forceinline__ void mlp1_unit(int b, int kc, int t, float* zs,
                                          const float* __restrict__ x,
                                          const float* __restrict__ poolS,
                                          const float* __restrict__ poolM,
                                          const float* __restrict__ We1,
                                          float* __restrict__ z1p) {
    __syncthreads();
    if (t < 80) {
        int k = kc * 80 + t;
        float v;
        if (k < 1024) {
            v = x[(size_t)b * 1024 + k];
        } else if (k < 1152) {
            int f = k - 1024;
            float s = 0.f;
#pragma unroll
            for (int it = 0; it < 16; ++it) s += poolS[(size_t)(b * 16 + it) * 128 + f];
            v = s * (1.f / 256.f);
        } else {
            int f = k - 1152;
            float mx = -3.4e38f;
#pragma unroll
            for (int it = 0; it < 16; ++it) mx = fmaxf(mx, poolM[(size_t)(b * 16 + it) * 128 + f]);
            v = mx;
        }
        zs[t] = v;
    }
    __syncthreads();
    const int o = t & 255, half = t >> 8;
    float s = 0.f;
#pragma unroll 8
    for (int kk = 0; kk < 40; ++kk)
        s += zs[half * 40 + kk] * We1[(size_t)(kc * 80 + half * 40 + kk) * 256 + o];
    z1p[(size_t)(b * 16 + kc) * 512 + half * 256 + o] = s;
}

// mlp2: combine 32 z1 partials; mlp2 k-split; mlp3. 512 threads.
__device__ __forceinline__ void mlp2_body(int b, int t, unsigned char* SM,
                                          const float* __restrict__ z1p,
                                          const float* __restrict__ be1,
                                          const float* __restrict__ We2,
                                          const float* __restrict__ be2,
                                          const float* __restrict__ We3,
                                          const float* __restrict__ be3,
                                          float* __restrict__ out) {
    float* z1s = (float*)SM;
    float* s2p = (float*)(SM + 1024);
    float* z2s = (float*)(SM + 2048);
    if (t < 256) {
        float s = be1[t];
#pragma unroll
        for (int kc = 0; kc < 16; ++kc) {
            size_t base = (size_t)(b * 16 + kc) * 512;
            s += z1p[base + t] + z1p[base + 256 + t];
        }
        z1s[t] = lrelu(s);
    }
    __syncthreads();
    if (t < 256) {
        int o = t & 31, g = t >> 5;
        float p = 0.f;
#pragma unroll
        for (int k = 0; k < 32; ++k) p += z1s[g * 32 + k] * We2[(g * 32 + k) * 32 + o];
        s2p[g * 32 + o] = p;
    }
    __syncthreads();
    if (t < 32) {
        float s2 = be2[t];
#pragma unroll
        for (int g = 0; g < 8; ++g) s2 += s2p[g * 32 + t];
        z2s[t] = lrelu(s2);
    }
    __syncthreads();
    if (t == 0) {
        float s3 = be3[0];
#pragma unroll
        for (int k = 0; k < 32; ++k) s3 += z2s[k] * We3[k];
        out[b] = s3;
    }
}

// ---------------- workspace layout ----------------
constexpr size_t O_MASK  = 0;                            // 2,097,152
constexpr size_t O_SRC   = 2097152;  constexpr size_t SRC_SZ = 327680;   // x3
constexpr size_t O_DST   = O_SRC + 3 * SRC_SZ;                           // x3
constexpr size_t O_AB    = O_DST + 3 * SRC_SZ;  constexpr size_t AB_SZ = 2097152;  // x2
constexpr size_t O_HT    = O_AB + 2 * AB_SZ;    constexpr size_t HT_SZ = 10485760; // x3
constexpr size_t O_WTX   = O_HT + 3 * HT_SZ;    constexpr size_t WTX_SZ = 409600;  // x8
constexpr size_t O_POOLS = O_WTX + 8 * WTX_SZ;
constexpr size_t O_POOLM = O_POOLS + 262144;
constexpr size_t O_Z1P   = O_POOLM + 262144;
constexpr size_t O_SYNC  = O_Z1P + 1048576;              // 16,384 B zeroed per iter

// =======================================================================================
// XCD-closed persistent kernel: 512 blocks x 512 threads.
// Registration (real XCC_ID + rank) -> 1 global rendezvous (control-only) ->
// 9 per-XCD phases with 8 fence-free per-XCD barriers. XCD x owns b in {x,x+8,x+16,x+24}
// and a private WT copy, so NO data ever crosses an XCD boundary.
// =======================================================================================
__global__ __launch_bounds__(512, 4) void k_mega(
    const float* __restrict__ x, const float* __restrict__ y_atoms,
    const int* __restrict__ bonds,
    const float* __restrict__ W1, const float* __restrict__ b1, const float* __restrict__ a1,
    const float* __restrict__ W2, const float* __restrict__ b2, const float* __restrict__ a2,
    const float* __restrict__ W3, const float* __restrict__ b3, const float* __restrict__ a3,
    const float* __restrict__ We1, const float* __restrict__ be1,
    const float* __restrict__ We2, const float* __restrict__ be2,
    const float* __restrict__ We3, const float* __restrict__ be3,
    char* __restrict__ ws, float* __restrict__ out) {
    __shared__ __align__(16) unsigned char SM[46976];
    __shared__ unsigned s_nfo[3];
    const int rb = blockIdx.x;
    const int t = threadIdx.x;
    const int hb = t >> 8, t2 = t & 255;

    unsigned char* maskp = (unsigned char*)(ws + O_MASK);
    unsigned* sync = (unsigned*)(ws + O_SYNC);
    float* poolS = (float*)(ws + O_POOLS);
    float* poolM = (float*)(ws + O_POOLM);
    float* z1p   = (float*)(ws + O_Z1P);

    // ---- registration + global rendezvous (control-only, no fences) ----
    if (t == 0) {
        unsigned xr;
        asm volatile("s_getreg_b32 %0, hwreg(HW_REG_XCC_ID)" : "=s"(xr));
        xr &= 7u;
        unsigned rk = __hip_atomic_fetch_add(&sync[SY_CNT + xr * 32], 1u,
                                             __ATOMIC_RELAXED, __HIP_MEMORY_SCOPE_AGENT);
        __hip_atomic_fetch_add(&sync[SY_GA + (rb & 7) * 32], 1u,
                               __ATOMIC_RELAXED, __HIP_MEMORY_SCOPE_AGENT);
        if (rb == 0) {
            unsigned s;
            do {
                __builtin_amdgcn_s_sleep(2);
                s = 0;
#pragma unroll
                for (int i = 0; i < 8; ++i)
                    s += __hip_atomic_load(&sync[SY_GA + i * 32],
                                           __ATOMIC_RELAXED, __HIP_MEMORY_SCOPE_AGENT);
            } while (s < NBLK);
#pragma unroll
            for (int g = 0; g < 16; ++g)
                __hip_atomic_store(&sync[SY_GR + g * 32], 1u,
                                   __ATOMIC_RELAXED, __HIP_MEMORY_SCOPE_AGENT);
        } else {
            unsigned* w = &sync[SY_GR + (rb >> 5) * 32];
            while (__hip_atomic_load(w, __ATOMIC_RELAXED, __HIP_MEMORY_SCOPE_AGENT) < 1u)
                __builtin_amdgcn_s_sleep(16);
        }
        s_nfo[0] = xr;
        s_nfo[1] = rk;
        s_nfo[2] = __hip_atomic_load(&sync[SY_CNT + xr * 32],
                                     __ATOMIC_RELAXED, __HIP_MEMORY_SCOPE_AGENT);
    }
    __syncthreads();
    const int xcd = (int)s_nfo[0];
    const int r = (int)s_nfo[1];
    const unsigned cnt = s_nfo[2];

    // per-XCD pointers/buffers
    unsigned short* WT1x = (unsigned short*)(ws + O_WTX + (size_t)xcd * WTX_SZ);
    unsigned short* WT2x = WT1x + 40960;                 // 81920 B in
    unsigned short* WT3x = WT2x + 81920;                 // +163840 B
    float* src0 = (float*)(ws + O_SRC);
    float* src1 = (float*)(ws + O_SRC + SRC_SZ);
    float* src2 = (float*)(ws + O_SRC + 2 * SRC_SZ);
    float* dst0 = (float*)(ws + O_DST);
    float* dst1 = (float*)(ws + O_DST + SRC_SZ);
    float* dst2 = (float*)(ws + O_DST + 2 * SRC_SZ);
    unsigned short* Ab0 = (unsigned short*)(ws + O_AB);
    unsigned short* Ab1 = (unsigned short*)(ws + O_AB + AB_SZ);
    unsigned short* hT0 = (unsigned short*)(ws + O_HT);
    unsigned short* hT1 = (unsigned short*)(ws + O_HT + HT_SZ);
    unsigned short* hT2 = (unsigned short*)(ws + O_HT + 2 * HT_SZ);

    // ---- P0: WT1 (own-XCD copy) ----
    for (int u = r; u < 10; u += cnt) wtrans(W1, WT1x, 64, u, t);
    xbar(sync, xcd, r, cnt, 1, t);

    // ---- P1: gemm1 + maskpack + WT2/WT3 ----
    for (int u = r; u < 20; u += cnt) {
        if (u < 10) wtrans(W2, WT2x, 128, u, t);
        else        wtrans(W3, WT3x, 128, u - 10, t);
    }
    for (int u = 2 * r + hb; u < 160; u += 2 * cnt) {
        int b = xcd + (u & 3) * 8;
        int mt = b * 4 + ((u >> 2) & 3), nt = u >> 4;
        gemm_body<64, 0>(mt, nt, t2, y_atoms, nullptr, WT1x, b1, a1, src0, dst0, hT0);
    }
    for (unsigned u = r * 512u + t; u < 65536u; u += cnt * 512u) {
        int b = xcd + (int)(u >> 14) * 8;
        maskpack(bonds, maskp, b * 16384 + (int)(u & 16383u));
    }
    xbar(sync, xcd, r, cnt, 2, t);

    // ---- P2: agg1 ----
    for (int u = r; u < 64; u += cnt)
        agg_body<0>(xcd + (u & 3) * 8, u >> 2, t, SM, hT0, src0, dst0, maskp,
                    Ab0, nullptr, nullptr);
    xbar(sync, xcd, r, cnt, 3, t);

    // ---- P3: gemm2 ----
    for (int u = 2 * r + hb; u < 160; u += 2 * cnt) {
        int b = xcd + (u & 3) * 8;
        int mt = b * 4 + ((u >> 2) & 3), nt = u >> 4;
        gemm_body<128, 1>(mt, nt, t2, nullptr, Ab0, WT2x, b2, a2, src1, dst1, hT1);
    }
    xbar(sync, xcd, r, cnt, 4, t);

    // ---- P4: agg2 ----
    for (int u = r; u < 64; u += cnt)
        agg_body<0>(xcd + (u & 3) * 8, u >> 2, t, SM, hT1, src1, dst1, maskp,
                    Ab1, nullptr, nullptr);
    xbar(sync, xcd, r, cnt, 5, t);

    // ---- P5: gemm3 ----
    for (int u = 2 * r + hb; u < 160; u += 2 * cnt) {
        int b = xcd + (u & 3) * 8;
        int mt = b * 4 + ((u >> 2) & 3), nt = u >> 4;
        gemm_body<128, 1>(mt, nt, t2, nullptr, Ab1, WT3x, b3, a3, src2, dst2, hT2);
    }
    xbar(sync, xcd, r, cnt, 6, t);

    // ---- P6: agg3 + pooling ----
    for (int u = r; u < 64; u += cnt)
        agg_body<1>(xcd + (u & 3) * 8, u >> 2, t, SM, hT2, src2, dst2, maskp,
                    nullptr, poolS, poolM);
    xbar(sync, xcd, r, cnt, 7, t);

    // ---- P7: mlp1 partials ----
    for (int u = r; u < 64; u += cnt)
        mlp1_unit(xcd + (u & 3) * 8, u >> 2, t, (float*)SM, x, poolS, poolM, We1, z1p);
    xbar(sync, xcd, r, cnt, 8, t);

    // ---- P8: mlp2/mlp3 ----
    for (int u = r; u < 4; u += cnt)
        mlp2_body(xcd + u * 8, t, SM, z1p, be1, We2, be2, We3, be3, out);
}

extern "C" void kernel_launch(void* const* d_in, const int* in_sizes, int n_in,
                              void* d_out, int out_size, void* d_ws, size_t ws_size,
                              hipStream_t stream) {
    const float* x       = (const float*)d_in[0];
    const float* y_atoms = (const float*)d_in[1];
    const int*   y_bonds = (const int*)d_in[2];
    const float* W1 = (const float*)d_in[3];
    const float* b1 = (const float*)d_in[4];
    const float* a1 = (const float*)d_in[5];
    const float* W2 = (const float*)d_in[6];
    const float* b2 = (const float*)d_in[7];
    const float* a2 = (const float*)d_in[8];
    const float* W3 = (const float*)d_in[9];
    const float* b3 = (const float*)d_in[10];
    const float* a3 = (const float*)d_in[11];
    const float* We1 = (const float*)d_in[12];
    const float* be1 = (const float*)d_in[13];
    const float* We2 = (const float*)d_in[14];
    const float* be2 = (const float*)d_in[15];
    const float* We3 = (const float*)d_in[16];
    const float* be3 = (const float*)d_in[17];
    float* out = (float*)d_out;
    char* ws = (char*)d_ws;

    hipMemsetAsync(ws + O_SYNC, 0, 16384, stream);
    k_mega<<<NBLK, 512, 0, stream>>>(
        x, y_atoms, y_bonds, W1, b1, a1, W2, b2, a2, W3, b3, a3,
        We1, be1, We2, be2, We3, be3, ws, out);
}